// Round 8
// baseline (41.407 us; speedup 1.0000x reference)
//
#include <hip/hip_runtime.h>

#define N_TOT 8192
#define BSZ   4096
#define DIM   256

typedef __attribute__((ext_vector_type(4))) float f32x4;
typedef __attribute__((ext_vector_type(4))) int   i32x4;
typedef __attribute__((ext_vector_type(8))) int   i32x8;

// zb is pre-scaled by sqrt(2*log2(e)) so that acc = 2*log2(e)*sim and
// exp(2*sim) == exp2(acc) with no extra multiplies in the epilogue.
#define PRESCALE 1.69864362f
#define SCALE1   0x7F7F7F7F    // E8M0 exponent 127 = 2^0 = 1.0 in every byte

__device__ __forceinline__ void async_copy16(const void* g, void* l) {
    __builtin_amdgcn_global_load_lds((const __attribute__((address_space(1))) void*)g,
                                     (__attribute__((address_space(3))) void*)l,
                                     16, 0, 0);
}

// ---------------------------------------------------------------------------
// Kernel 1: L2-normalize rows of zi/zj -> fp8 e4m3 zb[8192][256] (LINEAR rows,
// scaled by PRESCALE); fused positive-pair dots in fp32 (unscaled).
// ---------------------------------------------------------------------------
__global__ __launch_bounds__(256) void norm_kernel(const float* __restrict__ zi,
                                                   const float* __restrict__ zj,
                                                   unsigned char* __restrict__ zb,
                                                   float* __restrict__ posPart) {
    __shared__ float buf[2][256];
    const int wid  = threadIdx.x >> 6;
    const int lane = threadIdx.x & 63;
    const int pair = blockIdx.x * 2 + (wid & 1);    // 0..4095
    const bool isZj = (wid >= 2);
    const float* src = isZj ? (zj + (size_t)pair * DIM) : (zi + (size_t)pair * DIM);
    float4 v = ((const float4*)src)[lane];
    float ss = v.x * v.x + v.y * v.y + v.z * v.z + v.w * v.w;
    #pragma unroll
    for (int off = 1; off < 64; off <<= 1) ss += __shfl_xor(ss, off);
    float inv = 1.0f / fmaxf(sqrtf(ss), 1e-12f);
    float4 nv = make_float4(v.x * inv, v.y * inv, v.z * inv, v.w * inv);

    const int outRow = isZj ? (pair + BSZ) : pair;
    int pk = __builtin_amdgcn_cvt_pk_fp8_f32(nv.x * PRESCALE, nv.y * PRESCALE, 0, false);
    pk     = __builtin_amdgcn_cvt_pk_fp8_f32(nv.z * PRESCALE, nv.w * PRESCALE, pk, true);
    *(int*)(zb + (size_t)outRow * 256 + lane * 4) = pk;

    if (!isZj) ((float4*)&buf[wid & 1][0])[lane] = nv;
    __syncthreads();
    if (isZj) {
        float4 a = ((float4*)&buf[wid & 1][0])[lane];
        float d = a.x * nv.x + a.y * nv.y + a.z * nv.z + a.w * nv.w;
        #pragma unroll
        for (int off = 1; off < 64; off <<= 1) d += __shfl_xor(d, off);
        if (lane == 0) posPart[pair] = d;
    }
}

// ---------------------------------------------------------------------------
// Kernel 2: symmetric fused Z*Z^T -> exp2 -> partial row AND col sums.
// MX-scaled fp8: mfma_scale_f32_16x16x128_f8f6f4 with unit scales (0x7F).
// Upper-tri 2080 blocks, 128x128 tile, 4 waves (2x2), 64x64/wave.
// FULL K (256) staged upfront into 64 KB LDS: 2 K-phases x (A 16K + B 16K).
// Only 3 barriers + 1 real vmem wait per block.
//
// LDS tile [128 rows][128 B]; st_16x32 swizzle: 32B-pair index ^= row-bit-2
// (m201-verified conflict-free for this row width / read geometry).
// Involution applied on the gload_lds SOURCE (linear dest) + on the read.
// A-frag (16x16x128): lane holds row (l&15), k = (l>>4)*32 + 0..31 (one MX
// scale block), read as 2x b128 at pair (q ^ rowbit2)*32.
// C/D layout: shape-determined 16x16 (col=lane&15,row=(lane>>4)*4+reg).
// Slots: row-sums -> bj*2+wc; col-sums -> bi*2+wr.
// ---------------------------------------------------------------------------
__global__ __launch_bounds__(256, 2) void sim_kernel(const unsigned char* __restrict__ zb,
                                                     float* __restrict__ partial) {
    __shared__ alignas(16) char smem[65536];   // [kt][A|B] tiles; epi scratch

    const int t    = threadIdx.x;
    const int lane = t & 63;
    const int wid  = t >> 6;
    const int wr   = wid >> 1;     // 0..1
    const int wc   = wid & 1;      // 0..1
    const int g    = lane >> 4;    // 0..3  (k-quarter)
    const int c15  = lane & 15;

    // decode upper-triangular (bi, bj), bi <= bj, from linear block id
    const int k = blockIdx.x;                       // 0..2079
    int bi = (int)((129.0f - sqrtf(16641.0f - 8.0f * (float)k)) * 0.5f);
    while (bi * 64 - bi * (bi - 1) / 2 > k) bi--;
    while ((bi + 1) * 64 - (bi + 1) * bi / 2 <= k) bi++;
    const int bj = bi + (k - (bi * 64 - bi * (bi - 1) / 2));
    const bool diag = (bi == bj);

    const int row0 = bi * 128;
    const int col0 = bj * 128;

    f32x4 acc[4][4];
    #pragma unroll
    for (int m = 0; m < 4; m++)
        #pragma unroll
        for (int n = 0; n < 4; n++) acc[m][n] = (f32x4){0.f, 0.f, 0.f, 0.f};

    // Stage K-phase kt (A 128x128B + B 128x128B) : 8 gload_lds / thread.
    // Linear LDS dest slot e; source chunk applies the involution
    // c = (e&7) ^ ((row>>2 & 1) << 1).
    #define STAGE(kt) do {                                                      \
        _Pragma("unroll")                                                       \
        for (int i = 0; i < 4; i++) {                                           \
            const int e_  = i * 256 + t;       /* 16B slot 0..1023 */           \
            const int rr_ = e_ >> 3;           /* tile row 0..127 */            \
            const int c_  = (e_ & 7) ^ (((rr_ >> 2) & 1) << 1);                 \
            char* lb = smem + (kt) * 32768 + (i * 256 + wid * 64) * 16;         \
            const size_t ko = (size_t)(kt) * 128 + c_ * 16;                     \
            async_copy16(zb + (size_t)(row0 + rr_) * 256 + ko, lb);             \
            async_copy16(zb + (size_t)(col0 + rr_) * 256 + ko, lb + 16384);     \
        } } while (0)

    STAGE(0);
    STAGE(1);
    asm volatile("s_waitcnt vmcnt(8)" ::: "memory");   // phase-0 tiles landed
    __builtin_amdgcn_sched_barrier(0);
    __builtin_amdgcn_s_barrier();

    #pragma unroll
    for (int kt = 0; kt < 2; ++kt) {
        const char* Ab = smem + kt * 32768;
        const char* Bb = Ab + 16384;
        i32x8 af[4], bfr[4];
        #pragma unroll
        for (int m = 0; m < 4; m++) {
            const int rr = wr * 64 + m * 16 + c15;
            const int pp = g ^ ((rr >> 2) & 1);          // 32B pair index
            i32x4 lo = *(const i32x4*)(Ab + rr * 128 + pp * 32);
            i32x4 hi = *(const i32x4*)(Ab + rr * 128 + pp * 32 + 16);
            af[m] = __builtin_shufflevector(lo, hi, 0, 1, 2, 3, 4, 5, 6, 7);
        }
        #pragma unroll
        for (int n = 0; n < 4; n++) {
            const int rr = wc * 64 + n * 16 + c15;
            const int pp = g ^ ((rr >> 2) & 1);
            i32x4 lo = *(const i32x4*)(Bb + rr * 128 + pp * 32);
            i32x4 hi = *(const i32x4*)(Bb + rr * 128 + pp * 32 + 16);
            bfr[n] = __builtin_shufflevector(lo, hi, 0, 1, 2, 3, 4, 5, 6, 7);
        }
        #pragma unroll
        for (int m = 0; m < 4; m++)
            #pragma unroll
            for (int n = 0; n < 4; n++)
                acc[m][n] = __builtin_amdgcn_mfma_scale_f32_16x16x128_f8f6f4(
                    af[m], bfr[n], acc[m][n], 0, 0, 0, SCALE1, 0, SCALE1);

        if (kt == 0) {
            asm volatile("s_waitcnt vmcnt(0)" ::: "memory");  // phase-1 landed
            __builtin_amdgcn_sched_barrier(0);
            __builtin_amdgcn_s_barrier();
        }
    }
    #undef STAGE

    asm volatile("s_waitcnt lgkmcnt(0)" ::: "memory");
    __builtin_amdgcn_sched_barrier(0);
    __builtin_amdgcn_s_barrier();   // all tile reads done; smem reusable

    // ---- epilogue: exp2(acc); row sums (always) + col sums (off-diag) ----
    float rsum[4][4];
    float csum[4];
    #pragma unroll
    for (int m = 0; m < 4; m++)
        #pragma unroll
        for (int j = 0; j < 4; j++) rsum[m][j] = 0.f;
    #pragma unroll
    for (int n = 0; n < 4; n++) csum[n] = 0.f;

    const int colbase = col0 + wc * 64 + c15;
    const int rowbase = row0 + wr * 64 + (g << 2);
    #pragma unroll
    for (int m = 0; m < 4; m++) {
        #pragma unroll
        for (int n = 0; n < 4; n++) {
            const int colg = colbase + n * 16;
            #pragma unroll
            for (int j = 0; j < 4; j++) {
                const int rowg = rowbase + m * 16 + j;
                float e = exp2f(acc[m][n][j]);
                if (diag && rowg == colg) e = 0.0f;
                rsum[m][j] += e;
                csum[n] += e;
            }
        }
    }

    // col sums: reduce over the 4 row-groups; coalesced 16-lane stores
    if (!diag) {
        #pragma unroll
        for (int n = 0; n < 4; n++) {
            float s = csum[n];
            s += __shfl_xor(s, 16);
            s += __shfl_xor(s, 32);
            csum[n] = s;
        }
        if (lane < 16) {
            float* dst = partial + (size_t)(bi * 2 + wr) * N_TOT;
            #pragma unroll
            for (int n = 0; n < 4; n++)
                dst[colbase + n * 16] = csum[n];
        }
    }

    // row sums: wave-private LDS transpose [64][20] f32 -> coalesced store.
    float* sw = (float*)smem + wid * 1280;        // 5120 B per wave
    #pragma unroll
    for (int m = 0; m < 4; m++)
        #pragma unroll
        for (int j = 0; j < 4; j++)
            sw[(m * 16 + (g << 2) + j) * 20 + c15] = rsum[m][j];
    asm volatile("s_waitcnt lgkmcnt(0)" ::: "memory");
    __builtin_amdgcn_sched_barrier(0);
    f32x4 v0 = *(const f32x4*)(sw + lane * 20 + 0);
    f32x4 v1 = *(const f32x4*)(sw + lane * 20 + 4);
    f32x4 v2 = *(const f32x4*)(sw + lane * 20 + 8);
    f32x4 v3 = *(const f32x4*)(sw + lane * 20 + 12);
    float tot = (v0[0] + v0[1] + v0[2] + v0[3]) + (v1[0] + v1[1] + v1[2] + v1[3])
              + (v2[0] + v2[1] + v2[2] + v2[3]) + (v3[0] + v3[1] + v3[2] + v3[3]);
    partial[(size_t)(bj * 2 + wc) * N_TOT + row0 + wr * 64 + lane] = tot;
}

// ---------------------------------------------------------------------------
// Kernel 3: per-row sum of 128 partials -> log(negsum+eps). Grid 128 blocks,
// each block = 64 rows; wave w sums slots [w*32, w*32+32).
// ---------------------------------------------------------------------------
__global__ __launch_bounds__(256) void rowlog_kernel(const float* __restrict__ partial,
                                                     float* __restrict__ logPart) {
    const int lane = threadIdx.x & 63;
    const int w    = threadIdx.x >> 6;
    const int row  = blockIdx.x * 64 + lane;
    float s = 0.f;
    #pragma unroll 8
    for (int p = w * 32; p < w * 32 + 32; p++) s += partial[(size_t)p * N_TOT + row];
    __shared__ float red[4][64];
    red[w][lane] = s;
    __syncthreads();
    if (w == 0) {
        float tot = red[0][lane] + red[1][lane] + red[2][lane] + red[3][lane];
        float v = logf(tot + 1e-8f);
        #pragma unroll
        for (int off = 1; off < 64; off <<= 1) v += __shfl_xor(v, off);
        if (lane == 0) logPart[blockIdx.x] = v;
    }
}

// ---------------------------------------------------------------------------
// Kernel 4: final scalar: loss = mean(log terms) - 2*sum(dots)/BSZ
// ---------------------------------------------------------------------------
__global__ __launch_bounds__(256) void final_kernel(const float* __restrict__ logPart,
                                                    const float* __restrict__ posPart,
                                                    float* __restrict__ out) {
    const int t = threadIdx.x;
    float ps = 0.f;
    for (int i = t; i < BSZ; i += 256) ps += posPart[i];
    float ls = (t < 128) ? logPart[t] : 0.f;
    #pragma unroll
    for (int off = 1; off < 64; off <<= 1) {
        ps += __shfl_xor(ps, off);
        ls += __shfl_xor(ls, off);
    }
    __shared__ float redp[4], redl[4];
    const int lane = t & 63, wid = t >> 6;
    if (lane == 0) { redp[wid] = ps; redl[wid] = ls; }
    __syncthreads();
    if (t == 0) {
        const float posSum = redp[0] + redp[1] + redp[2] + redp[3];
        const float logSum = redl[0] + redl[1] + redl[2] + redl[3];
        out[0] = logSum / (float)N_TOT - 2.0f * posSum / (float)BSZ;
    }
}

extern "C" void kernel_launch(void* const* d_in, const int* in_sizes, int n_in,
                              void* d_out, int out_size, void* d_ws, size_t ws_size,
                              hipStream_t stream) {
    const float* zi = (const float*)d_in[0];
    const float* zj = (const float*)d_in[1];
    float* out = (float*)d_out;

    char* ws = (char*)d_ws;
    unsigned char* zb = (unsigned char*)ws;                      // 8192*256 = 2 MB
    float* partial     = (float*)(ws + (size_t)(4 << 20));       // 128*8192*4 = 4 MB
    float* logPart     = (float*)(ws + (size_t)(8 << 20));       // 128 floats
    float* posPart     = (float*)(ws + (size_t)(8 << 20) + 4096);// 4096 floats

    norm_kernel<<<2048, 256, 0, stream>>>(zi, zj, zb, posPart);
    sim_kernel<<<2080, 256, 0, stream>>>(zb, partial);
    rowlog_kernel<<<128, 256, 0, stream>>>(partial, logPart);
    final_kernel<<<1, 256, 0, stream>>>(logPart, posPart, out);
}

// Round 9
// 38.533 us; speedup vs baseline: 1.0746x; 1.0746x over previous
//
#include <hip/hip_runtime.h>

#define N_TOT 8192
#define BSZ   4096
#define DIM   256

typedef __attribute__((ext_vector_type(4)))  float f32x4;
typedef __attribute__((ext_vector_type(16))) float f32x16;
typedef __attribute__((ext_vector_type(4)))  int   i32x4;
typedef __attribute__((ext_vector_type(8)))  int   i32x8;

// zb is pre-scaled by sqrt(2*log2(e)) so that acc = 2*log2(e)*sim and
// exp(2*sim) == exp2(acc) with no extra multiplies in the epilogue.
#define PRESCALE 1.69864362f
#define SCALE1   0x7F7F7F7F    // E8M0 exponent 127 = 2^0 = 1.0 in every byte

__device__ __forceinline__ void async_copy16(const void* g, void* l) {
    __builtin_amdgcn_global_load_lds((const __attribute__((address_space(1))) void*)g,
                                     (__attribute__((address_space(3))) void*)l,
                                     16, 0, 0);
}

// ---------------------------------------------------------------------------
// Kernel 1: L2-normalize rows of zi/zj -> fp8 e4m3 zb[8192][256] (linear rows,
// scaled by PRESCALE); fused positive-pair dots in fp32 (unscaled).
// ---------------------------------------------------------------------------
__global__ __launch_bounds__(256) void norm_kernel(const float* __restrict__ zi,
                                                   const float* __restrict__ zj,
                                                   unsigned char* __restrict__ zb,
                                                   float* __restrict__ posPart) {
    __shared__ float buf[2][256];
    const int wid  = threadIdx.x >> 6;
    const int lane = threadIdx.x & 63;
    const int pair = blockIdx.x * 2 + (wid & 1);    // 0..4095
    const bool isZj = (wid >= 2);
    const float* src = isZj ? (zj + (size_t)pair * DIM) : (zi + (size_t)pair * DIM);
    float4 v = ((const float4*)src)[lane];
    float ss = v.x * v.x + v.y * v.y + v.z * v.z + v.w * v.w;
    #pragma unroll
    for (int off = 1; off < 64; off <<= 1) ss += __shfl_xor(ss, off);
    float inv = 1.0f / fmaxf(sqrtf(ss), 1e-12f);
    float4 nv = make_float4(v.x * inv, v.y * inv, v.z * inv, v.w * inv);

    const int outRow = isZj ? (pair + BSZ) : pair;
    int pk = __builtin_amdgcn_cvt_pk_fp8_f32(nv.x * PRESCALE, nv.y * PRESCALE, 0, false);
    pk     = __builtin_amdgcn_cvt_pk_fp8_f32(nv.z * PRESCALE, nv.w * PRESCALE, pk, true);
    *(int*)(zb + (size_t)outRow * 256 + lane * 4) = pk;

    if (!isZj) ((float4*)&buf[wid & 1][0])[lane] = nv;
    __syncthreads();
    if (isZj) {
        float4 a = ((float4*)&buf[wid & 1][0])[lane];
        float d = a.x * nv.x + a.y * nv.y + a.z * nv.z + a.w * nv.w;
        #pragma unroll
        for (int off = 1; off < 64; off <<= 1) d += __shfl_xor(d, off);
        if (lane == 0) posPart[pair] = d;
    }
}

// ---------------------------------------------------------------------------
// Kernel 2: symmetric fused Z*Z^T -> exp2 -> partial row AND col sums.
// MX-scaled fp8: mfma_scale_f32_32x32x64_f8f6f4 (unit scales) in ROUND 7's
// envelope: 128x128 tile, BK=64, 4 phases, 32 KB double-buffered LDS,
// counted vmcnt(4), 4 waves (2x2), 4 blocks/CU (16 waves/CU).
// Per wave-phase: 8 ds_read_b128 -> 4 MFMA (wave tile 64x64 = 2x2 of 32x32).
//
// LDS tile [128 rows][64 B]; chunk swizzle p = c ^ ((rr>>2)&3) (involution,
// applied on gload_lds SOURCE + on the read; 4 lanes/bank-quad = minimum).
// A/B frag (32x32x64): lane holds row (l&31), k = (l>>5)*32 + 0..31, read as
// 2x b128 at logical chunks (l>>5)*2, (l>>5)*2+1.
// C/D (32x32, m74/m101): col = lane&31, row = (reg&3)+8*(reg>>2)+4*(lane>>5).
// Slots: row-sums -> bj*2+wc; col-sums -> bi*2+wr.
// ---------------------------------------------------------------------------
__global__ __launch_bounds__(256, 4) void sim_kernel(const unsigned char* __restrict__ zb,
                                                     float* __restrict__ partial) {
    __shared__ alignas(16) char smem[32768];   // 2 dbuf x (A 8K + B 8K); epi scratch

    const int t    = threadIdx.x;
    const int lane = t & 63;
    const int wid  = t >> 6;
    const int wr   = wid >> 1;     // 0..1
    const int wc   = wid & 1;      // 0..1
    const int hi   = lane >> 5;    // 0..1
    const int r31  = lane & 31;

    // decode upper-triangular (bi, bj), bi <= bj, from linear block id
    const int k = blockIdx.x;                       // 0..2079
    int bi = (int)((129.0f - sqrtf(16641.0f - 8.0f * (float)k)) * 0.5f);
    while (bi * 64 - bi * (bi - 1) / 2 > k) bi--;
    while ((bi + 1) * 64 - (bi + 1) * bi / 2 <= k) bi++;
    const int bj = bi + (k - (bi * 64 - bi * (bi - 1) / 2));
    const bool diag = (bi == bj);

    const int row0 = bi * 128;
    const int col0 = bj * 128;

    f32x16 acc[2][2];
    #pragma unroll
    for (int mt = 0; mt < 2; mt++)
        #pragma unroll
        for (int nt = 0; nt < 2; nt++)
            #pragma unroll
            for (int r = 0; r < 16; r++) acc[mt][nt][r] = 0.f;

    // Stage one BK=64 K-tile (A 128x64B + B 128x64B) into buffer b.
    // 4 gload_lds / thread. Linear LDS dest slot e; source chunk applies the
    // involution g = p ^ ((row>>2)&3).
    #define STAGE(b, kt) do {                                                   \
        _Pragma("unroll")                                                       \
        for (int i = 0; i < 2; i++) {                                           \
            const int e_  = i * 256 + t;       /* 16B slot 0..511 */            \
            const int rr_ = e_ >> 2;           /* tile row 0..127 */            \
            const int p_  = e_ & 3;            /* phys chunk */                 \
            const int g_  = p_ ^ ((rr_ >> 2) & 3);   /* logical chunk */        \
            char* lb = smem + (b) * 16384 + (i * 256 + wid * 64) * 16;          \
            async_copy16(zb + (size_t)(row0 + rr_) * 256 + (kt) * 64 + g_ * 16, \
                         lb);                                                   \
            async_copy16(zb + (size_t)(col0 + rr_) * 256 + (kt) * 64 + g_ * 16, \
                         lb + 8192);                                            \
        } } while (0)

    STAGE(0, 0);   // prologue

    #pragma unroll
    for (int kt = 0; kt < 4; ++kt) {
        const int cur = kt & 1;
        if (kt < 3) {
            STAGE(cur ^ 1, kt + 1);
            asm volatile("s_waitcnt vmcnt(4)" ::: "memory");  // tile kt landed
        } else {
            asm volatile("s_waitcnt vmcnt(0)" ::: "memory");
        }
        __builtin_amdgcn_sched_barrier(0);
        __builtin_amdgcn_s_barrier();

        const char* Ab = smem + cur * 16384;
        const char* Bb = Ab + 8192;
        i32x8 af[2], bfr[2];
        #pragma unroll
        for (int mt = 0; mt < 2; mt++) {
            const int rr = wr * 64 + mt * 32 + r31;
            const int s  = (rr >> 2) & 3;
            i32x4 lo = *(const i32x4*)(Ab + rr * 64 + ((hi * 2)     ^ s) * 16);
            i32x4 hv = *(const i32x4*)(Ab + rr * 64 + ((hi * 2 + 1) ^ s) * 16);
            af[mt] = __builtin_shufflevector(lo, hv, 0, 1, 2, 3, 4, 5, 6, 7);
        }
        #pragma unroll
        for (int nt = 0; nt < 2; nt++) {
            const int rr = wc * 64 + nt * 32 + r31;
            const int s  = (rr >> 2) & 3;
            i32x4 lo = *(const i32x4*)(Bb + rr * 64 + ((hi * 2)     ^ s) * 16);
            i32x4 hv = *(const i32x4*)(Bb + rr * 64 + ((hi * 2 + 1) ^ s) * 16);
            bfr[nt] = __builtin_shufflevector(lo, hv, 0, 1, 2, 3, 4, 5, 6, 7);
        }
        #pragma unroll
        for (int mt = 0; mt < 2; mt++)
            #pragma unroll
            for (int nt = 0; nt < 2; nt++)
                acc[mt][nt] = __builtin_amdgcn_mfma_scale_f32_32x32x64_f8f6f4(
                    af[mt], bfr[nt], acc[mt][nt], 0, 0, 0, SCALE1, 0, SCALE1);

        __builtin_amdgcn_sched_barrier(0);
        __builtin_amdgcn_s_barrier();   // buf[cur] free for overwrite next iter
    }
    #undef STAGE

    // ---- epilogue (32x32 C/D layout): exp2; row sums + col sums ----
    // Wave-private sw[64][32] f32 (8 KB) with 16B-chunk XOR swizzle:
    //   word(row, c) = row*32 + ((c>>2 ^ (row&7))<<2) + (c&3)
    // writes: 2 rows x 32 cols per instr -> 2/bank (free);
    // reads: lane reads its row's 8 b128 at chunk q^(lane&7) -> min-touch.
    float* sw = (float*)smem + wid * 2048;
    float csum[2] = {0.f, 0.f};

    #pragma unroll
    for (int mt = 0; mt < 2; mt++) {
        #pragma unroll
        for (int reg = 0; reg < 16; reg++) {
            const int row_l = mt * 32 + (reg & 3) + ((reg >> 2) << 3) + (hi << 2);
            const int rowg  = row0 + wr * 64 + row_l;
            float r = 0.f;
            #pragma unroll
            for (int nt = 0; nt < 2; nt++) {
                float e = exp2f(acc[mt][nt][reg]);
                if (diag && rowg == (col0 + wc * 64 + nt * 32 + r31)) e = 0.0f;
                r += e;
                csum[nt] += e;
            }
            sw[row_l * 32 + ((((r31 >> 2) ^ (row_l & 7))) << 2) + (r31 & 3)] = r;
        }
    }

    // col sums: this lane covers 32 rows (its hi-group); partner has the rest.
    if (!diag) {
        float cv0 = csum[0] + __shfl_xor(csum[0], 32);
        float cv1 = csum[1] + __shfl_xor(csum[1], 32);
        const float cv = hi ? cv1 : cv0;   // lane stores col = hi*32 + r31 = lane
        partial[(size_t)(bi * 2 + wr) * N_TOT + col0 + wc * 64 + lane] = cv;
    }

    // row sums: read back this lane's row, coalesced 64-lane store.
    asm volatile("s_waitcnt lgkmcnt(0)" ::: "memory");
    __builtin_amdgcn_sched_barrier(0);
    float tot = 0.f;
    #pragma unroll
    for (int q = 0; q < 8; q++) {
        const int ch = q ^ (lane & 7);
        f32x4 v = *(const f32x4*)(sw + lane * 32 + ch * 4);
        tot += v[0] + v[1] + v[2] + v[3];
    }
    partial[(size_t)(bj * 2 + wc) * N_TOT + row0 + wr * 64 + lane] = tot;
}

// ---------------------------------------------------------------------------
// Kernel 3: per-row sum of 128 partials -> log(negsum+eps). Grid 128 blocks,
// each block = 64 rows; wave w sums slots [w*32, w*32+32).
// ---------------------------------------------------------------------------
__global__ __launch_bounds__(256) void rowlog_kernel(const float* __restrict__ partial,
                                                     float* __restrict__ logPart) {
    const int lane = threadIdx.x & 63;
    const int w    = threadIdx.x >> 6;
    const int row  = blockIdx.x * 64 + lane;
    float s = 0.f;
    #pragma unroll 8
    for (int p = w * 32; p < w * 32 + 32; p++) s += partial[(size_t)p * N_TOT + row];
    __shared__ float red[4][64];
    red[w][lane] = s;
    __syncthreads();
    if (w == 0) {
        float tot = red[0][lane] + red[1][lane] + red[2][lane] + red[3][lane];
        float v = logf(tot + 1e-8f);
        #pragma unroll
        for (int off = 1; off < 64; off <<= 1) v += __shfl_xor(v, off);
        if (lane == 0) logPart[blockIdx.x] = v;
    }
}

// ---------------------------------------------------------------------------
// Kernel 4: final scalar: loss = mean(log terms) - 2*sum(dots)/BSZ
// ---------------------------------------------------------------------------
__global__ __launch_bounds__(256) void final_kernel(const float* __restrict__ logPart,
                                                    const float* __restrict__ posPart,
                                                    float* __restrict__ out) {
    const int t = threadIdx.x;
    float ps = 0.f;
    for (int i = t; i < BSZ; i += 256) ps += posPart[i];
    float ls = (t < 128) ? logPart[t] : 0.f;
    #pragma unroll
    for (int off = 1; off < 64; off <<= 1) {
        ps += __shfl_xor(ps, off);
        ls += __shfl_xor(ls, off);
    }
    __shared__ float redp[4], redl[4];
    const int lane = t & 63, wid = t >> 6;
    if (lane == 0) { redp[wid] = ps; redl[wid] = ls; }
    __syncthreads();
    if (t == 0) {
        const float posSum = redp[0] + redp[1] + redp[2] + redp[3];
        const float logSum = redl[0] + redl[1] + redl[2] + redl[3];
        out[0] = logSum / (float)N_TOT - 2.0f * posSum / (float)BSZ;
    }
}

extern "C" void kernel_launch(void* const* d_in, const int* in_sizes, int n_in,
                              void* d_out, int out_size, void* d_ws, size_t ws_size,
                              hipStream_t stream) {
    const float* zi = (const float*)d_in[0];
    const float* zj = (const float*)d_in[1];
    float* out = (float*)d_out;

    char* ws = (char*)d_ws;
    unsigned char* zb = (unsigned char*)ws;                      // 8192*256 = 2 MB
    float* partial     = (float*)(ws + (size_t)(4 << 20));       // 128*8192*4 = 4 MB
    float* logPart     = (float*)(ws + (size_t)(8 << 20));       // 128 floats
    float* posPart     = (float*)(ws + (size_t)(8 << 20) + 4096);// 4096 floats

    norm_kernel<<<2048, 256, 0, stream>>>(zi, zj, zb, posPart);
    sim_kernel<<<2080, 256, 0, stream>>>(zb, partial);
    rowlog_kernel<<<128, 256, 0, stream>>>(partial, logPart);
    final_kernel<<<1, 256, 0, stream>>>(logPart, posPart, out);
}